// Round 4
// baseline (81.081 us; speedup 1.0000x reference)
//
#include <hip/hip_runtime.h>
#include <stdint.h>
#include <math.h>

// E = 1,000,000 episodes. x:(1,E,2) f32. Per episode (a,b):
//   probs = [(ca*cb)^2, (ca*sb)^2, (sa*sb)^2, (sa*cb)^2]  (CNOT swaps rows 2,3)
//   choice = argmax_c( log(p_c) + gumbel_c ),  gumbel from threefry2x32 key (0,42)
//   out = one_hot(choice, 4) flat (E*4) f32
//
// Random bits layout: JAX >= 0.5 defaults jax_threefry_partitionable=True.
// _threefry_random_bits_partitionable:
//   (hi, lo) = iota_2x32_shape((1,E,4))  -> flat index i = 4e + c, hi=0 here
//   (b1, b2) = threefry2x32(key=(0,42), x0=hi, x1=lo)
//   bits[i]  = b1 ^ b2          (bit_width 32 path)
// (The old non-partitionable split-counter layout was tested in R0-R3 with two
// log flavors and failed both -> layout was the structural error.)
//
// log f32 matches XLA:CPU's vectorized Cephes polynomial (GenerateVF32Log),
// with FMA contraction disabled (XLA emits separate fmul/fadd).

#define N_EP 1000000

__device__ __forceinline__ uint32_t rotl32(uint32_t x, int d) {
  return (x << d) | (x >> (32 - d));
}

__device__ __forceinline__ void threefry(uint32_t x0, uint32_t x1,
                                         uint32_t& o0, uint32_t& o1) {
  const uint32_t k0 = 0u;
  const uint32_t k1 = 42u;
  const uint32_t k2 = (0u ^ 42u ^ 0x1BD11BDAu);
  x0 += k0; x1 += k1;
#define R4A { x0 += x1; x1 = rotl32(x1,13); x1 ^= x0; \
              x0 += x1; x1 = rotl32(x1,15); x1 ^= x0; \
              x0 += x1; x1 = rotl32(x1,26); x1 ^= x0; \
              x0 += x1; x1 = rotl32(x1, 6); x1 ^= x0; }
#define R4B { x0 += x1; x1 = rotl32(x1,17); x1 ^= x0; \
              x0 += x1; x1 = rotl32(x1,29); x1 ^= x0; \
              x0 += x1; x1 = rotl32(x1,16); x1 ^= x0; \
              x0 += x1; x1 = rotl32(x1,24); x1 ^= x0; }
  R4A; x0 += k1; x1 += k2 + 1u;
  R4B; x0 += k2; x1 += k0 + 2u;
  R4A; x0 += k0; x1 += k1 + 3u;
  R4B; x0 += k1; x1 += k2 + 4u;
  R4A; x0 += k2; x1 += k0 + 5u;
#undef R4A
#undef R4B
  o0 = x0; o1 = x1;
}

// Bit-faithful port of XLA:CPU GenerateVF32Log (Cephes logf), no FMA.
__device__ float logf_xla(float input) {
#pragma clang fp contract(off)
  const float kMinNorm = __uint_as_float(0x00800000u);
  float t = fmaxf(input, kMinNorm);
  uint32_t ub = __float_as_uint(t);
  float e = (float)((int)(ub >> 23) - 126);
  float x = __uint_as_float((ub & 0x807fffffu) | 0x3f000000u);  // [0.5,1)
  const float kSqrtHf = 0.707106781186547524f;
  bool m = x < kSqrtHf;
  float tmp = m ? x : 0.0f;
  e = e - (m ? 1.0f : 0.0f);
  x = x - 1.0f;
  x = x + tmp;
  float z = x * x;
  float y = 7.0376836292E-2f;
  y = y * x + -1.1514610310E-1f;
  y = y * x +  1.1676998740E-1f;
  y = y * x + -1.2420140846E-1f;
  y = y * x +  1.4249322787E-1f;
  y = y * x + -1.6668057665E-1f;
  y = y * x +  2.0000714765E-1f;
  y = y * x + -2.4999993993E-1f;
  y = y * x +  3.3333331174E-1f;
  y = y * x;
  y = y * z;
  y = e * -2.12194440e-4f + y;
  y = z * -0.5f + y;
  x = x + y;
  x = e * 0.693359375f + x;
  if (input == 0.0f) x = -__builtin_inff();
  return x;
}

// JAX uniform(minval=tiny, maxval=1): f = bitcast((bits>>9)|0x3F800000) - 1.0;
// (maxval-minval) rounds to 1.0, the *1.0 is folded; u = max(tiny, f + tiny).
__device__ __forceinline__ float u_from_bits(uint32_t b) {
  const float tiny = 1.17549435e-38f;
  float f = __uint_as_float((b >> 9) | 0x3F800000u) - 1.0f;
  return fmaxf(tiny, f + tiny);
}

__device__ __forceinline__ float gumbel_f(uint32_t b) {
  float u = u_from_bits(b);
  float inner = logf_xla(u);     // < 0 (u < 1)
  float outer = logf_xla(-inner);
  return -outer;
}

__device__ __forceinline__ void do_episode(float a, float b,
                                           const uint32_t bits[4],
                                           float4* outp) {
  // sin/cos stay scalar glibc calls in XLA:CPU (near correctly rounded);
  // double eval + single rounding matches.
  float ca = (float)cos((double)a);
  float sa = (float)sin((double)a);
  float cb = (float)cos((double)b);
  float sb = (float)sin((double)b);
  float t0 = ca * cb;
  float t1 = ca * sb;
  float t2 = sa * sb;
  float t3 = sa * cb;
  float p0 = t0 * t0, p1 = t1 * t1, p2 = t2 * t2, p3 = t3 * t3;
  float y0 = logf_xla(p0) + gumbel_f(bits[0]);
  float y1 = logf_xla(p1) + gumbel_f(bits[1]);
  float y2 = logf_xla(p2) + gumbel_f(bits[2]);
  float y3 = logf_xla(p3) + gumbel_f(bits[3]);
  // jnp.argmax: first occurrence wins on ties -> strict greater
  int best = 0; float bv = y0;
  if (y1 > bv) { bv = y1; best = 1; }
  if (y2 > bv) { bv = y2; best = 2; }
  if (y3 > bv) { bv = y3; best = 3; }
  float4 o;
  o.x = (best == 0) ? 1.0f : 0.0f;
  o.y = (best == 1) ? 1.0f : 0.0f;
  o.z = (best == 2) ? 1.0f : 0.0f;
  o.w = (best == 3) ? 1.0f : 0.0f;
  *outp = o;
}

__global__ __launch_bounds__(256) void qcat_kernel(const float* __restrict__ x,
                                                   float* __restrict__ out) {
  int t = blockIdx.x * blockDim.x + threadIdx.x;
  if (t >= N_EP) return;

  // Partitionable threefry: counter = flat index 4t+c (hi word = 0),
  // 32-bit output = xor of the two threefry output words.
  uint32_t bits[4];
  uint32_t base = 4u * (uint32_t)t;
#pragma unroll
  for (int c = 0; c < 4; ++c) {
    uint32_t o0, o1;
    threefry(0u, base + (uint32_t)c, o0, o1);
    bits[c] = o0 ^ o1;
  }

  float2 ab = ((const float2*)x)[t];
  do_episode(ab.x, ab.y, bits, ((float4*)out) + t);
}

extern "C" void kernel_launch(void* const* d_in, const int* in_sizes, int n_in,
                              void* d_out, int out_size, void* d_ws, size_t ws_size,
                              hipStream_t stream) {
  const float* x = (const float*)d_in[0];
  float* out = (float*)d_out;
  dim3 block(256);
  dim3 grid((N_EP + 255) / 256);
  hipLaunchKernelGGL(qcat_kernel, grid, block, 0, stream, x, out);
}

// Round 5
// 75.368 us; speedup vs baseline: 1.0758x; 1.0758x over previous
//
#include <hip/hip_runtime.h>
#include <stdint.h>
#include <math.h>

// E = 1,000,000 episodes. x:(1,E,2) f32. Per episode (a,b):
//   probs = [(ca*cb)^2, (ca*sb)^2, (sa*sb)^2, (sa*cb)^2]  (CNOT swaps rows 2,3)
//   choice = argmax_c( log(p_c) + gumbel_c ),  gumbel from threefry2x32 key (0,42)
//   out = one_hot(choice, 4) flat (E*4) f32
//
// Random bits (JAX >= 0.5, jax_threefry_partitionable=True):
//   bits[i] = out0 ^ out1 of threefry2x32(key=(0,42), counter=(0, i)), i = 4e+c.
// VERIFIED bit-exact in R4 (absmax 0.0). Do not touch.
//
// log f32 = XLA:CPU GenerateVF32Log (Cephes), FMA contraction off. VERIFIED R4.
//
// R5 change: ocml double sin/cos (generic, slow) -> custom fp64 sincos with
// Cody-Waite reduction (inputs are N(0,1), |x| < ~6). ~0.6 ulp(double) accuracy
// -> identical f32 rounding vs the verified path except P~1e-9/call.

#define N_EP 1000000

__device__ __forceinline__ uint32_t rotl32(uint32_t x, int d) {
  return (x << d) | (x >> (32 - d));
}

__device__ __forceinline__ void threefry(uint32_t x0, uint32_t x1,
                                         uint32_t& o0, uint32_t& o1) {
  const uint32_t k0 = 0u;
  const uint32_t k1 = 42u;
  const uint32_t k2 = (0u ^ 42u ^ 0x1BD11BDAu);
  x0 += k0; x1 += k1;
#define R4A { x0 += x1; x1 = rotl32(x1,13); x1 ^= x0; \
              x0 += x1; x1 = rotl32(x1,15); x1 ^= x0; \
              x0 += x1; x1 = rotl32(x1,26); x1 ^= x0; \
              x0 += x1; x1 = rotl32(x1, 6); x1 ^= x0; }
#define R4B { x0 += x1; x1 = rotl32(x1,17); x1 ^= x0; \
              x0 += x1; x1 = rotl32(x1,29); x1 ^= x0; \
              x0 += x1; x1 = rotl32(x1,16); x1 ^= x0; \
              x0 += x1; x1 = rotl32(x1,24); x1 ^= x0; }
  R4A; x0 += k1; x1 += k2 + 1u;
  R4B; x0 += k2; x1 += k0 + 2u;
  R4A; x0 += k0; x1 += k1 + 3u;
  R4B; x0 += k1; x1 += k2 + 4u;
  R4A; x0 += k2; x1 += k0 + 5u;
#undef R4A
#undef R4B
  o0 = x0; o1 = x1;
}

// Bit-faithful port of XLA:CPU GenerateVF32Log (Cephes logf), no FMA.
__device__ float logf_xla(float input) {
#pragma clang fp contract(off)
  const float kMinNorm = __uint_as_float(0x00800000u);
  float t = fmaxf(input, kMinNorm);
  uint32_t ub = __float_as_uint(t);
  float e = (float)((int)(ub >> 23) - 126);
  float x = __uint_as_float((ub & 0x807fffffu) | 0x3f000000u);  // [0.5,1)
  const float kSqrtHf = 0.707106781186547524f;
  bool m = x < kSqrtHf;
  float tmp = m ? x : 0.0f;
  e = e - (m ? 1.0f : 0.0f);
  x = x - 1.0f;
  x = x + tmp;
  float z = x * x;
  float y = 7.0376836292E-2f;
  y = y * x + -1.1514610310E-1f;
  y = y * x +  1.1676998740E-1f;
  y = y * x + -1.2420140846E-1f;
  y = y * x +  1.4249322787E-1f;
  y = y * x + -1.6668057665E-1f;
  y = y * x +  2.0000714765E-1f;
  y = y * x + -2.4999993993E-1f;
  y = y * x +  3.3333331174E-1f;
  y = y * x;
  y = y * z;
  y = e * -2.12194440e-4f + y;
  y = z * -0.5f + y;
  x = x + y;
  x = e * 0.693359375f + x;
  if (input == 0.0f) x = -__builtin_inff();
  return x;
}

// Custom fp64 sincos, valid for |x| < ~1e5 (inputs are N(0,1), |x| < ~6).
// 2-term Cody-Waite pi/2 reduction + musl sin/cos kernels (~1e-16 rel err),
// then a single rounding to f32 -> matches correctly-rounded f32 except
// with probability ~1e-9 per call.
__device__ __forceinline__ void sincosf_cr(float xf, float* sp, float* cp) {
  double x = (double)xf;
  double dn = __builtin_rint(x * 6.36619772367581382433e-01);  // x * 2/pi
  int q = (int)dn;
  const double pio2_1  = 1.57079632673412561417e+00;  // 33 bits of pi/2
  const double pio2_1t = 6.07710050650619224932e-11;  // pi/2 - pio2_1
  double r = fma(-dn, pio2_1, x);
  r = fma(-dn, pio2_1t, r);
  double z = r * r;
  double w = z * z;
  // sin kernel (musl __sin, y=0)
  const double S1 = -1.66666666666666324348e-01;
  const double S2 =  8.33333333332248946124e-03;
  const double S3 = -1.98412698298579493134e-04;
  const double S4 =  2.75573137070700676789e-06;
  const double S5 = -2.50507602534068634195e-08;
  const double S6 =  1.58969099521155010221e-10;
  double rs = S2 + z * (S3 + z * S4) + z * w * (S5 + z * S6);
  double sinr = r + r * (z * (S1 + z * rs));
  // cos kernel (musl __cos, y=0)
  const double C1 =  4.16666666666666019037e-02;
  const double C2 = -1.38888888888741095749e-03;
  const double C3 =  2.48015872894767294178e-05;
  const double C4 = -2.75573143513906633035e-07;
  const double C5 =  2.08757232129817482790e-09;
  const double C6 = -1.13596475577881948265e-11;
  double rc = z * (C1 + z * (C2 + z * C3)) + w * w * (C4 + z * (C5 + z * C6));
  double hz = 0.5 * z;
  double ww = 1.0 - hz;
  double cosr = ww + (((1.0 - ww) - hz) + z * rc);
  // quadrant: 0:(s,c) 1:(c,-s) 2:(-s,-c) 3:(-c,s)  — branchless
  bool swap = q & 1;
  double s0 = swap ? cosr : sinr;
  double c0 = swap ? sinr : cosr;
  if (q & 2) s0 = -s0;
  if ((q + 1) & 2) c0 = -c0;
  *sp = (float)s0;
  *cp = (float)c0;
}

// JAX uniform(minval=tiny, maxval=1): f = bitcast((bits>>9)|0x3F800000) - 1.0;
// (maxval-minval) rounds to 1.0, the *1.0 is folded; u = max(tiny, f + tiny).
__device__ __forceinline__ float u_from_bits(uint32_t b) {
  const float tiny = 1.17549435e-38f;
  float f = __uint_as_float((b >> 9) | 0x3F800000u) - 1.0f;
  return fmaxf(tiny, f + tiny);
}

__device__ __forceinline__ float gumbel_f(uint32_t b) {
  float u = u_from_bits(b);
  float inner = logf_xla(u);     // < 0 (u < 1)
  float outer = logf_xla(-inner);
  return -outer;
}

__device__ __forceinline__ void do_episode(float a, float b,
                                           const uint32_t bits[4],
                                           float4* outp) {
  float ca, sa, cb, sb;
  sincosf_cr(a, &sa, &ca);
  sincosf_cr(b, &sb, &cb);
  float t0 = ca * cb;
  float t1 = ca * sb;
  float t2 = sa * sb;
  float t3 = sa * cb;
  float p0 = t0 * t0, p1 = t1 * t1, p2 = t2 * t2, p3 = t3 * t3;
  float y0 = logf_xla(p0) + gumbel_f(bits[0]);
  float y1 = logf_xla(p1) + gumbel_f(bits[1]);
  float y2 = logf_xla(p2) + gumbel_f(bits[2]);
  float y3 = logf_xla(p3) + gumbel_f(bits[3]);
  // jnp.argmax: first occurrence wins on ties -> strict greater
  int best = 0; float bv = y0;
  if (y1 > bv) { bv = y1; best = 1; }
  if (y2 > bv) { bv = y2; best = 2; }
  if (y3 > bv) { bv = y3; best = 3; }
  float4 o;
  o.x = (best == 0) ? 1.0f : 0.0f;
  o.y = (best == 1) ? 1.0f : 0.0f;
  o.z = (best == 2) ? 1.0f : 0.0f;
  o.w = (best == 3) ? 1.0f : 0.0f;
  *outp = o;
}

__global__ __launch_bounds__(256) void qcat_kernel(const float* __restrict__ x,
                                                   float* __restrict__ out) {
  int t = blockIdx.x * blockDim.x + threadIdx.x;
  if (t >= N_EP) return;

  uint32_t bits[4];
  uint32_t base = 4u * (uint32_t)t;
#pragma unroll
  for (int c = 0; c < 4; ++c) {
    uint32_t o0, o1;
    threefry(0u, base + (uint32_t)c, o0, o1);
    bits[c] = o0 ^ o1;
  }

  float2 ab = ((const float2*)x)[t];
  do_episode(ab.x, ab.y, bits, ((float4*)out) + t);
}

extern "C" void kernel_launch(void* const* d_in, const int* in_sizes, int n_in,
                              void* d_out, int out_size, void* d_ws, size_t ws_size,
                              hipStream_t stream) {
  const float* x = (const float*)d_in[0];
  float* out = (float*)d_out;
  dim3 block(256);
  dim3 grid((N_EP + 255) / 256);
  hipLaunchKernelGGL(qcat_kernel, grid, block, 0, stream, x, out);
}